// Round 11
// baseline (132.367 us; speedup 1.0000x reference)
//
#include <hip/hip_runtime.h>
#include <math.h>

#define HH 512
#define WW 512
#define NTOT (64u*512u*512u)
#define NBLK 4096
#define TS 64           // output tile edge
#define TROWS 68        // TS + 4 halo rows
#define TCH 10          // 8-wide chunks per row (80 cols: gx in [bx-8, bx+72))
#define TPIT 88         // LDS pitch (bf16): 176 B/row, 16B-aligned, light bank alias
#define NTASK (TROWS*TCH)   // 680
#define NITER 3             // ceil(NTASK/256)

typedef __attribute__((ext_vector_type(8))) short short8;
typedef __attribute__((ext_vector_type(4))) float f32x4;

__device__ __forceinline__ float fsqrtf(float x) { return __builtin_amdgcn_sqrtf(x); }

__device__ __forceinline__ float shrinkf(float x, float l) {
    float a = x - l, b = x + l;
    return x + 0.5f * (fsqrtf(__builtin_fmaf(a, a, 1.f)) - fsqrtf(__builtin_fmaf(b, b, 1.f)));
}

__device__ __forceinline__ float bf2f(unsigned int u) {
    union { unsigned int i; float f; } cv;
    cv.i = u << 16;
    return cv.f;
}
__device__ __forceinline__ float lo2f(unsigned int p) {
    union { unsigned int i; float f; } cv; cv.i = p << 16; return cv.f;
}
__device__ __forceinline__ float hi2f(unsigned int p) {
    union { unsigned int i; float f; } cv; cv.i = p & 0xffff0000u; return cv.f;
}

// v_cvt_pk_bf16_f32 (RNE): dst = bf16(lo) | (bf16(hi) << 16)
__device__ __forceinline__ unsigned int cvtpk(float lo, float hi) {
    unsigned int r;
    asm("v_cvt_pk_bf16_f32 %0, %1, %2" : "=v"(r) : "v"(lo), "v"(hi));
    return r;
}

__device__ __forceinline__ void bf8(uint4 u, float* f) {
    f[0] = bf2f(u.x & 0xffffu); f[1] = bf2f(u.x >> 16);
    f[2] = bf2f(u.y & 0xffffu); f[3] = bf2f(u.y >> 16);
    f[4] = bf2f(u.z & 0xffffu); f[5] = bf2f(u.z >> 16);
    f[6] = bf2f(u.w & 0xffffu); f[7] = bf2f(u.w >> 16);
}

// MFMA conv (Toeplitz): out[ct] += sum_ky A_ky(16x32) x B_ky(32x16)
//   A_ky[m][k] = tile[row0+m+ky][ct*16 + k]  (tile col t <-> gx = bx + t - 8)
//   B_ky[k][n] = w[ky][k-n-6] if 0 <= k-n-6 <= 4 else 0
// MODE 0: y (fp32) identity -> t1 bf16
// MODE 1: t1, shrink(n1(t1), l0) -> t2 bf16
// MODE 2: t1,t2, shrink(n2+n1, l1) -> t3 bf16 (OBF) / fp32 (!OBF)
// All modes: register-prefetch staging (1-ahead), 8 blocks/CU.
template <int MODE, bool OBF>
__global__ __launch_bounds__(256, 8) void conv_k(
    const float* __restrict__ yin,
    const unsigned short* __restrict__ t1,
    const unsigned short* __restrict__ t2,
    unsigned short* __restrict__ outbf,
    float* __restrict__ outf32,
    const float* __restrict__ wgt,
    const float* __restrict__ bias,
    const float* __restrict__ stats,
    const float* __restrict__ lambd,
    float* __restrict__ partials)
{
    __shared__ unsigned short tile[TROWS * TPIT];   // 11,968 B -> 8 blocks/CU

    const int tid = threadIdx.x;
    const int by = blockIdx.y * TS;
    const int bx = blockIdx.x * TS;
    const size_t ibase = (size_t)blockIdx.z * (HH * WW);

    float s1 = 0.f, h1 = 0.f, s2v = 0.f, h2 = 0.f, lam = 0.f;
    if constexpr (MODE == 1) { s1 = stats[0]; h1 = stats[1]; lam = lambd[0]; }
    if constexpr (MODE == 2) {
        s1 = stats[0]; h1 = stats[1]; s2v = stats[2]; h2 = stats[3]; lam = lambd[1];
    }

    // uniform weights -> SGPRs
    float wloc[25];
#pragma unroll
    for (int i = 0; i < 25; i++) wloc[i] = wgt[i];

    // ---- lane-local B fragments (no LDS): lane holds B[k=kb*8+j][n=lm] ----
    const int lane = tid & 63;
    const int lm = lane & 15;
    const int kb = lane >> 4;
    const int basei = kb * 8 - lm - 6;   // idx = basei + j, valid 0..4
    short8 bfr[5];
#pragma unroll
    for (int ky = 0; ky < 5; ky++) {
        unsigned pkw[4];
#pragma unroll
        for (int jj = 0; jj < 4; jj++) {
            float v0 = 0.f, v1 = 0.f;
            const int i0 = basei + 2 * jj, i1 = i0 + 1;
#pragma unroll
            for (int t = 0; t < 5; t++) {
                if (i0 == t) v0 = wloc[ky * 5 + t];
                if (i1 == t) v1 = wloc[ky * 5 + t];
            }
            pkw[jj] = cvtpk(v0, v1);
        }
        union { unsigned u[4]; short8 s; } cv;
        cv.u[0] = pkw[0]; cv.u[1] = pkw[1]; cv.u[2] = pkw[2]; cv.u[3] = pkw[3];
        bfr[ky] = cv.s;
    }

    // ---- staging: fused loop with 1-ahead prefetch (2 loads in flight) ----
    uint4 curA = make_uint4(0u,0u,0u,0u), curB = make_uint4(0u,0u,0u,0u);
    {
        const int task = tid;                    // first task
        const int row = task / TCH;
        const int ch  = task - row * TCH;
        const int gy  = by + row - 2;
        const int gx0 = bx + ch * 8 - 8;
        if (gy >= 0 && gy < HH && gx0 >= 0 && gx0 <= WW - 8) {
            const size_t g = ibase + (size_t)gy * WW + gx0;
            if constexpr (MODE == 0) {
                curA = *(const uint4*)(yin + g);
                curB = *(const uint4*)(yin + g + 4);
            } else if constexpr (MODE == 1) {
                curA = *(const uint4*)(t1 + g);
            } else {
                curA = *(const uint4*)(t1 + g);
                curB = *(const uint4*)(t2 + g);
            }
        }
    }
#pragma unroll
    for (int t = 0; t < NITER; t++) {
        // prefetch next task's data
        uint4 nxtA = make_uint4(0u,0u,0u,0u), nxtB = make_uint4(0u,0u,0u,0u);
        if (t + 1 < NITER) {
            const int ntsk = tid + (t + 1) * 256;
            const int row = ntsk / TCH;
            const int ch  = ntsk - row * TCH;
            const int gy  = by + row - 2;
            const int gx0 = bx + ch * 8 - 8;
            if (ntsk < NTASK && gy >= 0 && gy < HH && gx0 >= 0 && gx0 <= WW - 8) {
                const size_t g = ibase + (size_t)gy * WW + gx0;
                if constexpr (MODE == 0) {
                    nxtA = *(const uint4*)(yin + g);
                    nxtB = *(const uint4*)(yin + g + 4);
                } else if constexpr (MODE == 1) {
                    nxtA = *(const uint4*)(t1 + g);
                } else {
                    nxtA = *(const uint4*)(t1 + g);
                    nxtB = *(const uint4*)(t2 + g);
                }
            }
        }
        // transform current task and write LDS (OOB chunks store literal zero)
        const int task = tid + t * 256;
        if (task < NTASK) {
            const int row = task / TCH;
            const int ch  = task - row * TCH;
            uint4 pk = make_uint4(0u,0u,0u,0u);
            if constexpr (MODE == 0) {
                const float4 a = *(const float4*)&curA;
                const float4 b = *(const float4*)&curB;
                pk.x = cvtpk(a.x, a.y); pk.y = cvtpk(a.z, a.w);
                pk.z = cvtpk(b.x, b.y); pk.w = cvtpk(b.z, b.w);
            } else if constexpr (MODE == 1) {
                float f1[8]; bf8(curA, f1);
                float v[8];
#pragma unroll
                for (int k = 0; k < 8; k++)
                    v[k] = shrinkf(__builtin_fmaf(f1[k], s1, h1), lam);
                pk.x = cvtpk(v[0], v[1]); pk.y = cvtpk(v[2], v[3]);
                pk.z = cvtpk(v[4], v[5]); pk.w = cvtpk(v[6], v[7]);
            } else {
                float f1[8], f2[8]; bf8(curA, f1); bf8(curB, f2);
                float v[8];
#pragma unroll
                for (int k = 0; k < 8; k++) {
                    float x = __builtin_fmaf(f2[k], s2v, h2)
                            + __builtin_fmaf(f1[k], s1, h1);
                    v[k] = shrinkf(x, lam);
                }
                pk.x = cvtpk(v[0], v[1]); pk.y = cvtpk(v[2], v[3]);
                pk.z = cvtpk(v[4], v[5]); pk.w = cvtpk(v[6], v[7]);
            }
            // OOB chunk: transform ran on zeros, but reference zero-pads the
            // post-transform conv input -> store literal zero
            const int gy  = by + row - 2;
            const int gx0 = bx + ch * 8 - 8;
            if (!(gy >= 0 && gy < HH && gx0 >= 0 && gx0 <= WW - 8))
                pk = make_uint4(0u,0u,0u,0u);
            *(uint4*)&tile[row * TPIT + ch * 8] = pk;
        }
        curA = nxtA; curB = nxtB;
    }

    const float b0 = bias[0];
    __syncthreads();

    // ---- MFMA phase: wave wv owns 16 output rows x 64 cols ----
    const int wv = tid >> 6;
    const int r0w = wv * 16;

    f32x4 acc[4];
#pragma unroll
    for (int ct = 0; ct < 4; ct++)
        acc[ct] = (f32x4){0.f, 0.f, 0.f, 0.f};

#pragma unroll
    for (int ky = 0; ky < 5; ky++) {
        const short8 b = bfr[ky];
        const unsigned short* ab = &tile[(r0w + lm + ky) * TPIT + kb * 8];
#pragma unroll
        for (int ct = 0; ct < 4; ct++) {
            short8 a = *(const short8*)(ab + ct * 16);
            acc[ct] = __builtin_amdgcn_mfma_f32_16x16x32_bf16(a, b, acc[ct], 0, 0, 0);
        }
    }

    // ---- epilogue: lane holds rows kb*4+e, col lm of each 16x16 tile ----
    float s = 0.f, q = 0.f;
    const int grow0 = by + r0w + kb * 4;
#pragma unroll
    for (int ct = 0; ct < 4; ct++) {
        const f32x4 a = acc[ct];
        const size_t base = ibase + (size_t)grow0 * WW + bx + ct * 16 + lm;
        if constexpr (OBF) {
            unsigned p01 = cvtpk(a[0] + b0, a[1] + b0);
            unsigned p23 = cvtpk(a[2] + b0, a[3] + b0);
            outbf[base]          = (unsigned short)(p01 & 0xffffu);
            outbf[base + WW]     = (unsigned short)(p01 >> 16);
            outbf[base + 2 * WW] = (unsigned short)(p23 & 0xffffu);
            outbf[base + 3 * WW] = (unsigned short)(p23 >> 16);
            float fr0 = lo2f(p01), fr1 = hi2f(p01), fr2 = lo2f(p23), fr3 = hi2f(p23);
            s += fr0 + fr1 + fr2 + fr3;
            q = __builtin_fmaf(fr0, fr0, __builtin_fmaf(fr1, fr1,
                __builtin_fmaf(fr2, fr2, __builtin_fmaf(fr3, fr3, q))));
        } else {
            float f0 = a[0] + b0, f1v = a[1] + b0, f2v = a[2] + b0, f3v = a[3] + b0;
            outf32[base]          = f0;
            outf32[base + WW]     = f1v;
            outf32[base + 2 * WW] = f2v;
            outf32[base + 3 * WW] = f3v;
            s += f0 + f1v + f2v + f3v;
            q = __builtin_fmaf(f0, f0, __builtin_fmaf(f1v, f1v,
                __builtin_fmaf(f2v, f2v, __builtin_fmaf(f3v, f3v, q))));
        }
    }

    // ---- block reduction (LDS tree, reuse tile) ----
    __syncthreads();
    float* red = (float*)tile;
    red[tid] = s; red[256 + tid] = q;
    __syncthreads();
    for (int off = 128; off > 0; off >>= 1) {
        if (tid < off) { red[tid] += red[tid + off]; red[256 + tid] += red[256 + tid + off]; }
        __syncthreads();
    }
    if (tid == 0) {
        const int bid = (blockIdx.z * 8 + blockIdx.y) * 8 + blockIdx.x;
        partials[bid * 2] = red[0];
        partials[bid * 2 + 1] = red[256];
    }
}

__global__ __launch_bounds__(256) void finalize_k(
    const float* __restrict__ partials, float* __restrict__ stats, int stage,
    const float* __restrict__ gamma, const float* __restrict__ beta)
{
    __shared__ double rs[256], rq[256];
    const int tid = threadIdx.x;
    double s = 0.0, q = 0.0;
    for (int i = tid; i < NBLK; i += 256) { s += partials[2 * i]; q += partials[2 * i + 1]; }
    rs[tid] = s; rq[tid] = q;
    __syncthreads();
    for (int off = 128; off > 0; off >>= 1) {
        if (tid < off) { rs[tid] += rs[tid + off]; rq[tid] += rq[tid + off]; }
        __syncthreads();
    }
    if (tid == 0) {
        double mean = rs[0] / (double)NTOT;
        double var = rq[0] / (double)NTOT - mean * mean;
        double scl = (double)gamma[0] / sqrt(var + 1e-5);
        stats[2 * stage] = (float)scl;
        stats[2 * stage + 1] = (float)((double)beta[0] - mean * scl);
    }
}

// out = shrink(n3(t3) + n1(t1), lambd[2]); t3 bf16 (T3BF) or fp32 in io
template <bool T3BF>
__global__ __launch_bounds__(256) void final_k(
    const unsigned short* __restrict__ t1,
    const unsigned short* __restrict__ t3b,
    float* __restrict__ io,
    const float* __restrict__ stats, const float* __restrict__ lambd)
{
    const float s1 = stats[0], h1 = stats[1], s3 = stats[4], h3 = stats[5];
    const float lam = lambd[2];
    const size_t base = ((size_t)blockIdx.x * 256 + threadIdx.x) * 8;

    uint4 u1 = *(const uint4*)(t1 + base);
    float f1[8]; bf8(u1, f1);

    float t3v[8];
    if constexpr (T3BF) {
        uint4 u3 = *(const uint4*)(t3b + base);
        bf8(u3, t3v);
    } else {
        float4 a0 = *(const float4*)(io + base);
        float4 a1 = *(const float4*)(io + base + 4);
        t3v[0]=a0.x; t3v[1]=a0.y; t3v[2]=a0.z; t3v[3]=a0.w;
        t3v[4]=a1.x; t3v[5]=a1.y; t3v[6]=a1.z; t3v[7]=a1.w;
    }

    float r[8];
#pragma unroll
    for (int k = 0; k < 8; k++) {
        float v = __builtin_fmaf(t3v[k], s3, h3) + __builtin_fmaf(f1[k], s1, h1);
        r[k] = shrinkf(v, lam);
    }
    *(float4*)(io + base)     = make_float4(r[0], r[1], r[2], r[3]);
    *(float4*)(io + base + 4) = make_float4(r[4], r[5], r[6], r[7]);
}

extern "C" void kernel_launch(void* const* d_in, const int* in_sizes, int n_in,
                              void* d_out, int out_size, void* d_ws, size_t ws_size,
                              hipStream_t stream)
{
    const float* y     = (const float*)d_in[0];
    const float* wgt   = (const float*)d_in[1];
    const float* bias  = (const float*)d_in[2];
    const float* gamma = (const float*)d_in[3];
    const float* beta  = (const float*)d_in[4];
    const float* lambd = (const float*)d_in[5];
    float* out = (float*)d_out;

    char* ws = (char*)d_ws;
    unsigned short* t1 = (unsigned short*)ws;                    // 33,554,432 B
    unsigned short* t2 = (unsigned short*)(ws + 33554432ull);    // 33,554,432 B
    unsigned short* t3 = (unsigned short*)(ws + 67108864ull);    // 33,554,432 B
    const bool t3bf = (ws_size >= 100696088ull);
    const size_t poff = t3bf ? 100663296ull : 67108864ull;
    float* partials = (float*)(ws + poff);                       // 32,768 B
    float* stats    = (float*)(ws + poff + 32768ull);            // 24 B

    dim3 grid(8, 8, 64), blk(256);
    conv_k<0, true><<<grid, blk, 0, stream>>>(y, nullptr, nullptr, t1, nullptr,
                                              wgt, bias, stats, lambd, partials);
    finalize_k<<<1, blk, 0, stream>>>(partials, stats, 0, gamma, beta);
    conv_k<1, true><<<grid, blk, 0, stream>>>(nullptr, t1, nullptr, t2, nullptr,
                                              wgt, bias, stats, lambd, partials);
    finalize_k<<<1, blk, 0, stream>>>(partials, stats, 1, gamma, beta);
    if (t3bf) {
        conv_k<2, true><<<grid, blk, 0, stream>>>(nullptr, t1, t2, t3, nullptr,
                                                  wgt, bias, stats, lambd, partials);
        finalize_k<<<1, blk, 0, stream>>>(partials, stats, 2, gamma, beta);
        final_k<true><<<8192, blk, 0, stream>>>(t1, t3, out, stats, lambd);
    } else {
        conv_k<2, false><<<grid, blk, 0, stream>>>(nullptr, t1, t2, nullptr, out,
                                                   wgt, bias, stats, lambd, partials);
        finalize_k<<<1, blk, 0, stream>>>(partials, stats, 2, gamma, beta);
        final_k<false><<<8192, blk, 0, stream>>>(t1, nullptr, out, stats, lambd);
    }
}

// Round 12
// 106.701 us; speedup vs baseline: 1.2405x; 1.2405x over previous
//
#include <hip/hip_runtime.h>
#include <math.h>

#define HH 512
#define WW 512
#define NTOT (64u*512u*512u)
#define NBLK 1024
#define TS 128          // output tile edge
#define TROWS 132       // TS + 4 halo rows
#define TCH 18          // 8-wide chunks per row (144 cols: gx in [bx-8, bx+136))
#define TPIT 152        // LDS pitch (bf16): 304 B/row, 16B-aligned
#define NTASK (TROWS*TCH)   // 2376
#define NITER 10            // ceil(NTASK/256)

typedef __attribute__((ext_vector_type(8))) short short8;
typedef __attribute__((ext_vector_type(4))) float f32x4;

__device__ __forceinline__ float fsqrtf(float x) { return __builtin_amdgcn_sqrtf(x); }

__device__ __forceinline__ float shrinkf(float x, float l) {
    float a = x - l, b = x + l;
    return x + 0.5f * (fsqrtf(__builtin_fmaf(a, a, 1.f)) - fsqrtf(__builtin_fmaf(b, b, 1.f)));
}

__device__ __forceinline__ float bf2f(unsigned int u) {
    union { unsigned int i; float f; } cv;
    cv.i = u << 16;
    return cv.f;
}
__device__ __forceinline__ float lo2f(unsigned int p) {
    union { unsigned int i; float f; } cv; cv.i = p << 16; return cv.f;
}
__device__ __forceinline__ float hi2f(unsigned int p) {
    union { unsigned int i; float f; } cv; cv.i = p & 0xffff0000u; return cv.f;
}

// v_cvt_pk_bf16_f32 (RNE): dst = bf16(lo) | (bf16(hi) << 16)
__device__ __forceinline__ unsigned int cvtpk(float lo, float hi) {
    unsigned int r;
    asm("v_cvt_pk_bf16_f32 %0, %1, %2" : "=v"(r) : "v"(lo), "v"(hi));
    return r;
}

__device__ __forceinline__ void bf8(uint4 u, float* f) {
    f[0] = bf2f(u.x & 0xffffu); f[1] = bf2f(u.x >> 16);
    f[2] = bf2f(u.y & 0xffffu); f[3] = bf2f(u.y >> 16);
    f[4] = bf2f(u.z & 0xffffu); f[5] = bf2f(u.z >> 16);
    f[6] = bf2f(u.w & 0xffffu); f[7] = bf2f(u.w >> 16);
}

// MFMA conv (Toeplitz): out[ct] += sum_ky A_ky(16x32) x B_ky(32x16)
//   A_ky[m][k] = tile[row0+m+ky][ct*16 + k]  (tile col t <-> gx = bx + t - 8)
//   B_ky[k][n] = w[ky][k-n-6] if 0 <= k-n-6 <= 4 else 0
// MODE 0: y (fp32) identity -> t1 bf16
// MODE 1: t1, shrink(n1(t1), l0) -> t2 bf16
// MODE 2: t1,t2, shrink(n2+n1, l1) -> t3 bf16 (OBF) / fp32 (!OBF)
// Staging: depth-3 software pipeline, explicitly named registers.
template <int MODE, bool OBF>
__global__ __launch_bounds__(256, 4) void conv_k(
    const float* __restrict__ yin,
    const unsigned short* __restrict__ t1,
    const unsigned short* __restrict__ t2,
    unsigned short* __restrict__ outbf,
    float* __restrict__ outf32,
    const float* __restrict__ wgt,
    const float* __restrict__ bias,
    const float* __restrict__ stats,
    const float* __restrict__ lambd,
    float* __restrict__ partials)
{
    __shared__ unsigned short tile[TROWS * TPIT];   // 40,128 B -> 4 blocks/CU

    const int tid = threadIdx.x;
    const int by = blockIdx.y * TS;
    const int bx = blockIdx.x * TS;
    const size_t ibase = (size_t)blockIdx.z * (HH * WW);

    float s1 = 0.f, h1 = 0.f, s2v = 0.f, h2 = 0.f, lam = 0.f;
    if constexpr (MODE == 1) { s1 = stats[0]; h1 = stats[1]; lam = lambd[0]; }
    if constexpr (MODE == 2) {
        s1 = stats[0]; h1 = stats[1]; s2v = stats[2]; h2 = stats[3]; lam = lambd[1];
    }

    // uniform weights -> SGPRs
    float wloc[25];
#pragma unroll
    for (int i = 0; i < 25; i++) wloc[i] = wgt[i];

    // ---- lane-local B fragments (no LDS): lane holds B[k=kb*8+j][n=lm] ----
    const int lane = tid & 63;
    const int lm = lane & 15;
    const int kb = lane >> 4;
    const int basei = kb * 8 - lm - 6;   // idx = basei + j, valid 0..4
    short8 bfr[5];
#pragma unroll
    for (int ky = 0; ky < 5; ky++) {
        unsigned pkw[4];
#pragma unroll
        for (int jj = 0; jj < 4; jj++) {
            float v0 = 0.f, v1 = 0.f;
            const int i0 = basei + 2 * jj, i1 = i0 + 1;
#pragma unroll
            for (int t = 0; t < 5; t++) {
                if (i0 == t) v0 = wloc[ky * 5 + t];
                if (i1 == t) v1 = wloc[ky * 5 + t];
            }
            pkw[jj] = cvtpk(v0, v1);
        }
        union { unsigned u[4]; short8 s; } cv;
        cv.u[0] = pkw[0]; cv.u[1] = pkw[1]; cv.u[2] = pkw[2]; cv.u[3] = pkw[3];
        bfr[ky] = cv.s;
    }

    // ---- staging: depth-3 pipeline, named regs (sA0..sB2), ~3 loads in flight
    auto loadT = [&](int task, uint4& A, uint4& B) {
        A = make_uint4(0u,0u,0u,0u); B = make_uint4(0u,0u,0u,0u);
        const int row = task / TCH;
        const int ch  = task - row * TCH;
        const int gy  = by + row - 2;
        const int gx0 = bx + ch * 8 - 8;
        if (task < NTASK && gy >= 0 && gy < HH && gx0 >= 0 && gx0 <= WW - 8) {
            const size_t g = ibase + (size_t)gy * WW + gx0;
            if constexpr (MODE == 0) {
                A = *(const uint4*)(yin + g);
                B = *(const uint4*)(yin + g + 4);
            } else if constexpr (MODE == 1) {
                A = *(const uint4*)(t1 + g);
            } else {
                A = *(const uint4*)(t1 + g);
                B = *(const uint4*)(t2 + g);
            }
        }
    };

    auto procT = [&](int task, uint4 A, uint4 B) {
        const int row = task / TCH;
        const int ch  = task - row * TCH;
        uint4 pk = make_uint4(0u,0u,0u,0u);
        if constexpr (MODE == 0) {
            const float4 a = *(const float4*)&A;
            const float4 b = *(const float4*)&B;
            pk.x = cvtpk(a.x, a.y); pk.y = cvtpk(a.z, a.w);
            pk.z = cvtpk(b.x, b.y); pk.w = cvtpk(b.z, b.w);
        } else if constexpr (MODE == 1) {
            float f1[8]; bf8(A, f1);
            float v[8];
#pragma unroll
            for (int k = 0; k < 8; k++)
                v[k] = shrinkf(__builtin_fmaf(f1[k], s1, h1), lam);
            pk.x = cvtpk(v[0], v[1]); pk.y = cvtpk(v[2], v[3]);
            pk.z = cvtpk(v[4], v[5]); pk.w = cvtpk(v[6], v[7]);
        } else {
            float f1[8], f2[8]; bf8(A, f1); bf8(B, f2);
            float v[8];
#pragma unroll
            for (int k = 0; k < 8; k++) {
                float x = __builtin_fmaf(f2[k], s2v, h2)
                        + __builtin_fmaf(f1[k], s1, h1);
                v[k] = shrinkf(x, lam);
            }
            pk.x = cvtpk(v[0], v[1]); pk.y = cvtpk(v[2], v[3]);
            pk.z = cvtpk(v[4], v[5]); pk.w = cvtpk(v[6], v[7]);
        }
        // OOB chunk: transform ran on zeros, but reference zero-pads the
        // post-transform conv input -> store literal zero
        const int gy  = by + row - 2;
        const int gx0 = bx + ch * 8 - 8;
        if (!(gy >= 0 && gy < HH && gx0 >= 0 && gx0 <= WW - 8))
            pk = make_uint4(0u,0u,0u,0u);
        *(uint4*)&tile[row * TPIT + ch * 8] = pk;
    };

    uint4 sA0, sB0, sA1, sB1, sA2, sB2;
    loadT(tid,        sA0, sB0);
    loadT(tid + 256,  sA1, sB1);
    loadT(tid + 512,  sA2, sB2);
#pragma unroll
    for (int t = 0; t < NITER; t++) {
        const int task = tid + t * 256;
        if (task < NTASK) procT(task, sA0, sB0);
        sA0 = sA1; sB0 = sB1;
        sA1 = sA2; sB1 = sB2;
        if (t + 3 < NITER) {
            loadT(tid + (t + 3) * 256, sA2, sB2);
        } else {
            sA2 = make_uint4(0u,0u,0u,0u); sB2 = make_uint4(0u,0u,0u,0u);
        }
    }

    const float b0 = bias[0];
    __syncthreads();

    // ---- MFMA phase: wave wv owns 32 output rows x 128 cols ----
    const int wv = tid >> 6;
    const int r0w = wv * 32;

    f32x4 acc[2][8];
#pragma unroll
    for (int st = 0; st < 2; st++)
#pragma unroll
        for (int ct = 0; ct < 8; ct++)
            acc[st][ct] = (f32x4){0.f, 0.f, 0.f, 0.f};

#pragma unroll
    for (int ky = 0; ky < 5; ky++) {
        const short8 b = bfr[ky];
#pragma unroll
        for (int st = 0; st < 2; st++) {
            const unsigned short* ab = &tile[(r0w + st * 16 + lm + ky) * TPIT + kb * 8];
#pragma unroll
            for (int ct = 0; ct < 8; ct++) {
                short8 a = *(const short8*)(ab + ct * 16);
                acc[st][ct] = __builtin_amdgcn_mfma_f32_16x16x32_bf16(a, b, acc[st][ct], 0, 0, 0);
            }
        }
    }

    // ---- epilogue: lane holds rows kb*4+e, col lm of each 16x16 tile ----
    float s = 0.f, q = 0.f;
#pragma unroll
    for (int st = 0; st < 2; st++) {
#pragma unroll
        for (int ct = 0; ct < 8; ct++) {
            const f32x4 a = acc[st][ct];
            const int grow0 = by + r0w + st * 16 + kb * 4;
            const size_t base = ibase + (size_t)grow0 * WW + bx + ct * 16 + lm;
            if constexpr (OBF) {
                unsigned p01 = cvtpk(a[0] + b0, a[1] + b0);
                unsigned p23 = cvtpk(a[2] + b0, a[3] + b0);
                outbf[base]          = (unsigned short)(p01 & 0xffffu);
                outbf[base + WW]     = (unsigned short)(p01 >> 16);
                outbf[base + 2 * WW] = (unsigned short)(p23 & 0xffffu);
                outbf[base + 3 * WW] = (unsigned short)(p23 >> 16);
                float fr0 = lo2f(p01), fr1 = hi2f(p01), fr2 = lo2f(p23), fr3 = hi2f(p23);
                s += fr0 + fr1 + fr2 + fr3;
                q = __builtin_fmaf(fr0, fr0, __builtin_fmaf(fr1, fr1,
                    __builtin_fmaf(fr2, fr2, __builtin_fmaf(fr3, fr3, q))));
            } else {
                float f0 = a[0] + b0, f1v = a[1] + b0, f2v = a[2] + b0, f3v = a[3] + b0;
                outf32[base]          = f0;
                outf32[base + WW]     = f1v;
                outf32[base + 2 * WW] = f2v;
                outf32[base + 3 * WW] = f3v;
                s += f0 + f1v + f2v + f3v;
                q = __builtin_fmaf(f0, f0, __builtin_fmaf(f1v, f1v,
                    __builtin_fmaf(f2v, f2v, __builtin_fmaf(f3v, f3v, q))));
            }
        }
    }

    // ---- block reduction (LDS tree, reuse tile) ----
    __syncthreads();
    float* red = (float*)tile;
    red[tid] = s; red[256 + tid] = q;
    __syncthreads();
    for (int off = 128; off > 0; off >>= 1) {
        if (tid < off) { red[tid] += red[tid + off]; red[256 + tid] += red[256 + tid + off]; }
        __syncthreads();
    }
    if (tid == 0) {
        const int bid = (blockIdx.z * 4 + blockIdx.y) * 4 + blockIdx.x;
        partials[bid * 2] = red[0];
        partials[bid * 2 + 1] = red[256];
    }
}

__global__ __launch_bounds__(256) void finalize_k(
    const float* __restrict__ partials, float* __restrict__ stats, int stage,
    const float* __restrict__ gamma, const float* __restrict__ beta)
{
    __shared__ double rs[256], rq[256];
    const int tid = threadIdx.x;
    double s = 0.0, q = 0.0;
    for (int i = tid; i < NBLK; i += 256) { s += partials[2 * i]; q += partials[2 * i + 1]; }
    rs[tid] = s; rq[tid] = q;
    __syncthreads();
    for (int off = 128; off > 0; off >>= 1) {
        if (tid < off) { rs[tid] += rs[tid + off]; rq[tid] += rq[tid + off]; }
        __syncthreads();
    }
    if (tid == 0) {
        double mean = rs[0] / (double)NTOT;
        double var = rq[0] / (double)NTOT - mean * mean;
        double scl = (double)gamma[0] / sqrt(var + 1e-5);
        stats[2 * stage] = (float)scl;
        stats[2 * stage + 1] = (float)((double)beta[0] - mean * scl);
    }
}

// out = shrink(n3(t3) + n1(t1), lambd[2]); t3 bf16 (T3BF) or fp32 in io
template <bool T3BF>
__global__ __launch_bounds__(256) void final_k(
    const unsigned short* __restrict__ t1,
    const unsigned short* __restrict__ t3b,
    float* __restrict__ io,
    const float* __restrict__ stats, const float* __restrict__ lambd)
{
    const float s1 = stats[0], h1 = stats[1], s3 = stats[4], h3 = stats[5];
    const float lam = lambd[2];
    const size_t base = ((size_t)blockIdx.x * 256 + threadIdx.x) * 8;

    uint4 u1 = *(const uint4*)(t1 + base);
    float f1[8]; bf8(u1, f1);

    float t3v[8];
    if constexpr (T3BF) {
        uint4 u3 = *(const uint4*)(t3b + base);
        bf8(u3, t3v);
    } else {
        float4 a0 = *(const float4*)(io + base);
        float4 a1 = *(const float4*)(io + base + 4);
        t3v[0]=a0.x; t3v[1]=a0.y; t3v[2]=a0.z; t3v[3]=a0.w;
        t3v[4]=a1.x; t3v[5]=a1.y; t3v[6]=a1.z; t3v[7]=a1.w;
    }

    float r[8];
#pragma unroll
    for (int k = 0; k < 8; k++) {
        float v = __builtin_fmaf(t3v[k], s3, h3) + __builtin_fmaf(f1[k], s1, h1);
        r[k] = shrinkf(v, lam);
    }
    *(float4*)(io + base)     = make_float4(r[0], r[1], r[2], r[3]);
    *(float4*)(io + base + 4) = make_float4(r[4], r[5], r[6], r[7]);
}

extern "C" void kernel_launch(void* const* d_in, const int* in_sizes, int n_in,
                              void* d_out, int out_size, void* d_ws, size_t ws_size,
                              hipStream_t stream)
{
    const float* y     = (const float*)d_in[0];
    const float* wgt   = (const float*)d_in[1];
    const float* bias  = (const float*)d_in[2];
    const float* gamma = (const float*)d_in[3];
    const float* beta  = (const float*)d_in[4];
    const float* lambd = (const float*)d_in[5];
    float* out = (float*)d_out;

    char* ws = (char*)d_ws;
    unsigned short* t1 = (unsigned short*)ws;                    // 33,554,432 B
    unsigned short* t2 = (unsigned short*)(ws + 33554432ull);    // 33,554,432 B
    unsigned short* t3 = (unsigned short*)(ws + 67108864ull);    // 33,554,432 B
    const bool t3bf = (ws_size >= 100696088ull);
    const size_t poff = t3bf ? 100663296ull : 67108864ull;
    float* partials = (float*)(ws + poff);                       // 8,192 B used
    float* stats    = (float*)(ws + poff + 32768ull);            // 24 B

    dim3 grid(4, 4, 64), blk(256);
    conv_k<0, true><<<grid, blk, 0, stream>>>(y, nullptr, nullptr, t1, nullptr,
                                              wgt, bias, stats, lambd, partials);
    finalize_k<<<1, blk, 0, stream>>>(partials, stats, 0, gamma, beta);
    conv_k<1, true><<<grid, blk, 0, stream>>>(nullptr, t1, nullptr, t2, nullptr,
                                              wgt, bias, stats, lambd, partials);
    finalize_k<<<1, blk, 0, stream>>>(partials, stats, 1, gamma, beta);
    if (t3bf) {
        conv_k<2, true><<<grid, blk, 0, stream>>>(nullptr, t1, t2, t3, nullptr,
                                                  wgt, bias, stats, lambd, partials);
        finalize_k<<<1, blk, 0, stream>>>(partials, stats, 2, gamma, beta);
        final_k<true><<<8192, blk, 0, stream>>>(t1, t3, out, stats, lambd);
    } else {
        conv_k<2, false><<<grid, blk, 0, stream>>>(nullptr, t1, t2, nullptr, out,
                                                   wgt, bias, stats, lambd, partials);
        finalize_k<<<1, blk, 0, stream>>>(partials, stats, 2, gamma, beta);
        final_k<false><<<8192, blk, 0, stream>>>(t1, nullptr, out, stats, lambd);
    }
}

// Round 13
// 97.837 us; speedup vs baseline: 1.3529x; 1.0906x over previous
//
#include <hip/hip_runtime.h>
#include <math.h>

#define HH 512
#define WW 512
#define NTOT (64u*512u*512u)
#define NBLK 1024
#define TS 128          // output tile edge
#define TROWS 132       // TS + 4 halo rows
#define TCH 18          // 8-wide chunks per row (144 cols: gx in [bx-8, bx+136))
#define TPIT 152        // LDS pitch (bf16): 304 B/row, 16B-aligned
#define NTASK (TROWS*TCH)   // 2376
#define NITER 10            // ceil(NTASK/256)

typedef __attribute__((ext_vector_type(8))) short short8;
typedef __attribute__((ext_vector_type(4))) float f32x4;

__device__ __forceinline__ float fsqrtf(float x) { return __builtin_amdgcn_sqrtf(x); }

__device__ __forceinline__ float shrinkf(float x, float l) {
    float a = x - l, b = x + l;
    return x + 0.5f * (fsqrtf(__builtin_fmaf(a, a, 1.f)) - fsqrtf(__builtin_fmaf(b, b, 1.f)));
}

__device__ __forceinline__ float bf2f(unsigned int u) {
    union { unsigned int i; float f; } cv;
    cv.i = u << 16;
    return cv.f;
}
__device__ __forceinline__ float lo2f(unsigned int p) {
    union { unsigned int i; float f; } cv; cv.i = p << 16; return cv.f;
}
__device__ __forceinline__ float hi2f(unsigned int p) {
    union { unsigned int i; float f; } cv; cv.i = p & 0xffff0000u; return cv.f;
}

// v_cvt_pk_bf16_f32 (RNE): dst = bf16(lo) | (bf16(hi) << 16)
__device__ __forceinline__ unsigned int cvtpk(float lo, float hi) {
    unsigned int r;
    asm("v_cvt_pk_bf16_f32 %0, %1, %2" : "=v"(r) : "v"(lo), "v"(hi));
    return r;
}

__device__ __forceinline__ void bf8(uint4 u, float* f) {
    f[0] = bf2f(u.x & 0xffffu); f[1] = bf2f(u.x >> 16);
    f[2] = bf2f(u.y & 0xffffu); f[3] = bf2f(u.y >> 16);
    f[4] = bf2f(u.z & 0xffffu); f[5] = bf2f(u.z >> 16);
    f[6] = bf2f(u.w & 0xffffu); f[7] = bf2f(u.w >> 16);
}

// In-LDS deterministic stats reduce: 1024 partial pairs -> (scale, shift).
// EXACT same summation order as the old finalize_k (thread tid sums
// i = tid + 256k, then 256-entry tree) -> bit-identical stats.
__device__ __forceinline__ void stats_reduce(
    const float* __restrict__ part, double* rs, double* rq, int tid,
    float gam, float bet, float& scl_out, float& shf_out)
{
    double sd = 0.0, qd = 0.0;
#pragma unroll
    for (int k = 0; k < 4; k++) {
        const int i = tid + k * 256;
        sd += (double)part[2 * i];
        qd += (double)part[2 * i + 1];
    }
    rs[tid] = sd; rq[tid] = qd;
    __syncthreads();
    for (int off = 128; off > 0; off >>= 1) {
        if (tid < off) { rs[tid] += rs[tid + off]; rq[tid] += rq[tid + off]; }
        __syncthreads();
    }
    const double mean = rs[0] / (double)NTOT;
    const double var  = rq[0] / (double)NTOT - mean * mean;
    const double scl  = (double)gam / sqrt(var + 1e-5);
    scl_out = (float)scl;
    shf_out = (float)((double)bet - mean * scl);
    __syncthreads();   // before LDS reuse
}

// MFMA conv (Toeplitz): out[ct] += sum_ky A_ky(16x32) x B_ky(32x16)
//   A_ky[m][k] = tile[row0+m+ky][ct*16 + k]  (tile col t <-> gx = bx + t - 8)
//   B_ky[k][n] = w[ky][k-n-6] if 0 <= k-n-6 <= 4 else 0
// MODE 0: y (fp32) identity -> t1 bf16; writes partials P (no stats needed)
// MODE 1: reduces Pprev -> (s1,h1); t1 -> shrink(n1,l0) -> t2; writes (s1,h1)
//         to statsOut (block 0) and partials P
// MODE 2: reduces Pprev -> (s2,h2); reads (s1,h1) from statsIn;
//         t1,t2 -> shrink(n2+n1,l1) -> t3 bf16 (OBF) / fp32 (!OBF); partials P
template <int MODE, bool OBF>
__global__ __launch_bounds__(256, 4) void conv_k(
    const float* __restrict__ yin,
    const unsigned short* __restrict__ t1,
    const unsigned short* __restrict__ t2,
    unsigned short* __restrict__ outbf,
    float* __restrict__ outf32,
    const float* __restrict__ wgt,
    const float* __restrict__ bias,
    const float* __restrict__ prevPart,
    const float* __restrict__ statsIn,
    float* __restrict__ statsOut,
    const float* __restrict__ gamma,
    const float* __restrict__ beta,
    const float* __restrict__ lambd,
    float* __restrict__ partials)
{
    __shared__ unsigned short tile[TROWS * TPIT];   // 40,128 B -> 4 blocks/CU

    const int tid = threadIdx.x;
    const int by = blockIdx.y * TS;
    const int bx = blockIdx.x * TS;
    const size_t ibase = (size_t)blockIdx.z * (HH * WW);

    // uniform weights -> SGPRs
    float wloc[25];
#pragma unroll
    for (int i = 0; i < 25; i++) wloc[i] = wgt[i];

    // ---- lane-local B fragments (no LDS): lane holds B[k=kb*8+j][n=lm] ----
    const int lane = tid & 63;
    const int lm = lane & 15;
    const int kb = lane >> 4;
    const int basei = kb * 8 - lm - 6;   // idx = basei + j, valid 0..4
    short8 bfr[5];
#pragma unroll
    for (int ky = 0; ky < 5; ky++) {
        unsigned pkw[4];
#pragma unroll
        for (int jj = 0; jj < 4; jj++) {
            float v0 = 0.f, v1 = 0.f;
            const int i0 = basei + 2 * jj, i1 = i0 + 1;
#pragma unroll
            for (int t = 0; t < 5; t++) {
                if (i0 == t) v0 = wloc[ky * 5 + t];
                if (i1 == t) v1 = wloc[ky * 5 + t];
            }
            pkw[jj] = cvtpk(v0, v1);
        }
        union { unsigned u[4]; short8 s; } cv;
        cv.u[0] = pkw[0]; cv.u[1] = pkw[1]; cv.u[2] = pkw[2]; cv.u[3] = pkw[3];
        bfr[ky] = cv.s;
    }

    // ---- staging pipeline helpers (depth-3, named regs) ----
    auto loadT = [&](int task, uint4& A, uint4& B) {
        A = make_uint4(0u,0u,0u,0u); B = make_uint4(0u,0u,0u,0u);
        const int row = task / TCH;
        const int ch  = task - row * TCH;
        const int gy  = by + row - 2;
        const int gx0 = bx + ch * 8 - 8;
        if (task < NTASK && gy >= 0 && gy < HH && gx0 >= 0 && gx0 <= WW - 8) {
            const size_t g = ibase + (size_t)gy * WW + gx0;
            if constexpr (MODE == 0) {
                A = *(const uint4*)(yin + g);
                B = *(const uint4*)(yin + g + 4);
            } else if constexpr (MODE == 1) {
                A = *(const uint4*)(t1 + g);
            } else {
                A = *(const uint4*)(t1 + g);
                B = *(const uint4*)(t2 + g);
            }
        }
    };

    // issue first 3 tasks' loads BEFORE stats reduce (latency overlap)
    uint4 sA0, sB0, sA1, sB1, sA2, sB2;
    loadT(tid,        sA0, sB0);
    loadT(tid + 256,  sA1, sB1);
    loadT(tid + 512,  sA2, sB2);

    // ---- in-kernel stats (replaces finalize_k launches) ----
    float s1 = 0.f, h1 = 0.f, s2v = 0.f, h2 = 0.f, lam = 0.f;
    if constexpr (MODE == 1) {
        stats_reduce(prevPart, (double*)tile, ((double*)tile) + 256, tid,
                     gamma[0], beta[0], s1, h1);
        lam = lambd[0];
        if (tid == 0 && blockIdx.x == 0 && blockIdx.y == 0 && blockIdx.z == 0) {
            statsOut[0] = s1; statsOut[1] = h1;
        }
    }
    if constexpr (MODE == 2) {
        stats_reduce(prevPart, (double*)tile, ((double*)tile) + 256, tid,
                     gamma[0], beta[0], s2v, h2);
        s1 = statsIn[0]; h1 = statsIn[1];
        lam = lambd[1];
    }

    auto procT = [&](int task, uint4 A, uint4 B) {
        const int row = task / TCH;
        const int ch  = task - row * TCH;
        uint4 pk = make_uint4(0u,0u,0u,0u);
        if constexpr (MODE == 0) {
            const float4 a = *(const float4*)&A;
            const float4 b = *(const float4*)&B;
            pk.x = cvtpk(a.x, a.y); pk.y = cvtpk(a.z, a.w);
            pk.z = cvtpk(b.x, b.y); pk.w = cvtpk(b.z, b.w);
        } else if constexpr (MODE == 1) {
            float f1[8]; bf8(A, f1);
            float v[8];
#pragma unroll
            for (int k = 0; k < 8; k++)
                v[k] = shrinkf(__builtin_fmaf(f1[k], s1, h1), lam);
            pk.x = cvtpk(v[0], v[1]); pk.y = cvtpk(v[2], v[3]);
            pk.z = cvtpk(v[4], v[5]); pk.w = cvtpk(v[6], v[7]);
        } else {
            float f1[8], f2[8]; bf8(A, f1); bf8(B, f2);
            float v[8];
#pragma unroll
            for (int k = 0; k < 8; k++) {
                float x = __builtin_fmaf(f2[k], s2v, h2)
                        + __builtin_fmaf(f1[k], s1, h1);
                v[k] = shrinkf(x, lam);
            }
            pk.x = cvtpk(v[0], v[1]); pk.y = cvtpk(v[2], v[3]);
            pk.z = cvtpk(v[4], v[5]); pk.w = cvtpk(v[6], v[7]);
        }
        // OOB chunk: transform ran on zeros, but reference zero-pads the
        // post-transform conv input -> store literal zero
        const int gy  = by + row - 2;
        const int gx0 = bx + ch * 8 - 8;
        if (!(gy >= 0 && gy < HH && gx0 >= 0 && gx0 <= WW - 8))
            pk = make_uint4(0u,0u,0u,0u);
        *(uint4*)&tile[row * TPIT + ch * 8] = pk;
    };

#pragma unroll
    for (int t = 0; t < NITER; t++) {
        const int task = tid + t * 256;
        if (task < NTASK) procT(task, sA0, sB0);
        sA0 = sA1; sB0 = sB1;
        sA1 = sA2; sB1 = sB2;
        if (t + 3 < NITER) {
            loadT(tid + (t + 3) * 256, sA2, sB2);
        } else {
            sA2 = make_uint4(0u,0u,0u,0u); sB2 = make_uint4(0u,0u,0u,0u);
        }
    }

    const float b0 = bias[0];
    __syncthreads();

    // ---- MFMA phase: wave wv owns 32 output rows x 128 cols ----
    const int wv = tid >> 6;
    const int r0w = wv * 32;

    f32x4 acc[2][8];
#pragma unroll
    for (int st = 0; st < 2; st++)
#pragma unroll
        for (int ct = 0; ct < 8; ct++)
            acc[st][ct] = (f32x4){0.f, 0.f, 0.f, 0.f};

#pragma unroll
    for (int ky = 0; ky < 5; ky++) {
        const short8 b = bfr[ky];
#pragma unroll
        for (int st = 0; st < 2; st++) {
            const unsigned short* ab = &tile[(r0w + st * 16 + lm + ky) * TPIT + kb * 8];
#pragma unroll
            for (int ct = 0; ct < 8; ct++) {
                short8 a = *(const short8*)(ab + ct * 16);
                acc[st][ct] = __builtin_amdgcn_mfma_f32_16x16x32_bf16(a, b, acc[st][ct], 0, 0, 0);
            }
        }
    }

    // ---- epilogue: lane holds rows kb*4+e, col lm of each 16x16 tile ----
    float s = 0.f, q = 0.f;
#pragma unroll
    for (int st = 0; st < 2; st++) {
#pragma unroll
        for (int ct = 0; ct < 8; ct++) {
            const f32x4 a = acc[st][ct];
            const int grow0 = by + r0w + st * 16 + kb * 4;
            const size_t base = ibase + (size_t)grow0 * WW + bx + ct * 16 + lm;
            if constexpr (OBF) {
                unsigned p01 = cvtpk(a[0] + b0, a[1] + b0);
                unsigned p23 = cvtpk(a[2] + b0, a[3] + b0);
                outbf[base]          = (unsigned short)(p01 & 0xffffu);
                outbf[base + WW]     = (unsigned short)(p01 >> 16);
                outbf[base + 2 * WW] = (unsigned short)(p23 & 0xffffu);
                outbf[base + 3 * WW] = (unsigned short)(p23 >> 16);
                float fr0 = lo2f(p01), fr1 = hi2f(p01), fr2 = lo2f(p23), fr3 = hi2f(p23);
                s += fr0 + fr1 + fr2 + fr3;
                q = __builtin_fmaf(fr0, fr0, __builtin_fmaf(fr1, fr1,
                    __builtin_fmaf(fr2, fr2, __builtin_fmaf(fr3, fr3, q))));
            } else {
                float f0 = a[0] + b0, f1v = a[1] + b0, f2v = a[2] + b0, f3v = a[3] + b0;
                outf32[base]          = f0;
                outf32[base + WW]     = f1v;
                outf32[base + 2 * WW] = f2v;
                outf32[base + 3 * WW] = f3v;
                s += f0 + f1v + f2v + f3v;
                q = __builtin_fmaf(f0, f0, __builtin_fmaf(f1v, f1v,
                    __builtin_fmaf(f2v, f2v, __builtin_fmaf(f3v, f3v, q))));
            }
        }
    }

    // ---- block reduction (LDS tree, reuse tile) ----
    __syncthreads();
    float* red = (float*)tile;
    red[tid] = s; red[256 + tid] = q;
    __syncthreads();
    for (int off = 128; off > 0; off >>= 1) {
        if (tid < off) { red[tid] += red[tid + off]; red[256 + tid] += red[256 + tid + off]; }
        __syncthreads();
    }
    if (tid == 0) {
        const int bid = (blockIdx.z * 4 + blockIdx.y) * 4 + blockIdx.x;
        partials[bid * 2] = red[0];
        partials[bid * 2 + 1] = red[256];
    }
}

// out = shrink(n3(t3) + n1(t1), lambd[2]); reduces P3 -> (s3,h3) in-kernel.
// Grid: 1024 blocks x 8 grid-stride chunks.
template <bool T3BF>
__global__ __launch_bounds__(256) void final_k(
    const unsigned short* __restrict__ t1,
    const unsigned short* __restrict__ t3b,
    float* __restrict__ io,
    const float* __restrict__ p3,
    const float* __restrict__ statsIn,
    const float* __restrict__ gamma,
    const float* __restrict__ beta,
    const float* __restrict__ lambd)
{
    __shared__ double rbuf[512];
    const int tid = threadIdx.x;

    float s3, h3;
    stats_reduce(p3, rbuf, rbuf + 256, tid, gamma[0], beta[0], s3, h3);
    const float s1 = statsIn[0], h1 = statsIn[1];
    const float lam = lambd[2];

#pragma unroll
    for (int c = 0; c < 8; c++) {
        const size_t idx = ((size_t)c * 1024 + blockIdx.x) * 256 + tid;
        const size_t base = idx * 8;

        uint4 u1 = *(const uint4*)(t1 + base);
        float f1[8]; bf8(u1, f1);

        float t3v[8];
        if constexpr (T3BF) {
            uint4 u3 = *(const uint4*)(t3b + base);
            bf8(u3, t3v);
        } else {
            float4 a0 = *(const float4*)(io + base);
            float4 a1 = *(const float4*)(io + base + 4);
            t3v[0]=a0.x; t3v[1]=a0.y; t3v[2]=a0.z; t3v[3]=a0.w;
            t3v[4]=a1.x; t3v[5]=a1.y; t3v[6]=a1.z; t3v[7]=a1.w;
        }

        float r[8];
#pragma unroll
        for (int k = 0; k < 8; k++) {
            float v = __builtin_fmaf(t3v[k], s3, h3) + __builtin_fmaf(f1[k], s1, h1);
            r[k] = shrinkf(v, lam);
        }
        *(float4*)(io + base)     = make_float4(r[0], r[1], r[2], r[3]);
        *(float4*)(io + base + 4) = make_float4(r[4], r[5], r[6], r[7]);
    }
}

extern "C" void kernel_launch(void* const* d_in, const int* in_sizes, int n_in,
                              void* d_out, int out_size, void* d_ws, size_t ws_size,
                              hipStream_t stream)
{
    const float* y     = (const float*)d_in[0];
    const float* wgt   = (const float*)d_in[1];
    const float* bias  = (const float*)d_in[2];
    const float* gamma = (const float*)d_in[3];
    const float* beta  = (const float*)d_in[4];
    const float* lambd = (const float*)d_in[5];
    float* out = (float*)d_out;

    char* ws = (char*)d_ws;
    unsigned short* t1 = (unsigned short*)ws;                    // 33,554,432 B
    unsigned short* t2 = (unsigned short*)(ws + 33554432ull);    // 33,554,432 B
    unsigned short* t3 = (unsigned short*)(ws + 67108864ull);    // 33,554,432 B
    const bool t3bf = (ws_size >= 100696088ull);
    const size_t poff = t3bf ? 100663296ull : 67108864ull;
    float* p1    = (float*)(ws + poff);                // 8 KB
    float* p2    = (float*)(ws + poff + 8192ull);      // 8 KB
    float* p3    = (float*)(ws + poff + 16384ull);     // 8 KB
    float* stats = (float*)(ws + poff + 24576ull);     // 8 B

    dim3 grid(4, 4, 64), blk(256);
    conv_k<0, true><<<grid, blk, 0, stream>>>(y, nullptr, nullptr, t1, nullptr,
                                              wgt, bias, nullptr, nullptr, nullptr,
                                              gamma, beta, lambd, p1);
    conv_k<1, true><<<grid, blk, 0, stream>>>(nullptr, t1, nullptr, t2, nullptr,
                                              wgt, bias, p1, nullptr, stats,
                                              gamma, beta, lambd, p2);
    if (t3bf) {
        conv_k<2, true><<<grid, blk, 0, stream>>>(nullptr, t1, t2, t3, nullptr,
                                                  wgt, bias, p2, stats, nullptr,
                                                  gamma, beta, lambd, p3);
        final_k<true><<<1024, blk, 0, stream>>>(t1, t3, out, p3, stats,
                                                gamma, beta, lambd);
    } else {
        conv_k<2, false><<<grid, blk, 0, stream>>>(nullptr, t1, t2, nullptr, out,
                                                   wgt, bias, p2, stats, nullptr,
                                                   gamma, beta, lambd, p3);
        final_k<false><<<1024, blk, 0, stream>>>(t1, nullptr, out, p3, stats,
                                                 gamma, beta, lambd);
    }
}